// Round 1
// baseline (227.786 us; speedup 1.0000x reference)
//
#include <hip/hip_runtime.h>

// RenderingModel: scatter-add of 64x64 filters at N particle positions onto a
// 512x512 canvas (cropped). Implemented as a GATHER: each block owns a 32x32
// output tile, each thread owns 4 pixels in registers. Phase 1 compacts the
// particles whose 64x64 window intersects the tile into an LDS list; phase 2
// accumulates predicated filter loads. No atomics on the output, no zero-init
// needed (every output pixel is written exactly once at the end).

#define H_  512
#define W_  512
#define FH_ 64
#define FW_ 64
#define TILE_ 32
#define NMAX_ 8192

__global__ __launch_bounds__(256)
void render_tile_kernel(const int* __restrict__ phw,
                        const float* __restrict__ filters,
                        float* __restrict__ out, int n) {
    __shared__ unsigned int s_list[NMAX_];
    __shared__ int s_cnt;

    const int t   = threadIdx.x;
    const int tx0 = blockIdx.x * TILE_;
    const int ty0 = blockIdx.y * TILE_;

    if (t == 0) s_cnt = 0;
    __syncthreads();

    // ---- Phase 1: cooperative bbox test + compaction into LDS ----
    // Particle (part,row,col) contributes to output y in [row-32, row+31],
    // x in [col-32, col+31]. Tile covers [ty0, ty0+31] x [tx0, tx0+31].
    for (int k = t; k < n; k += 256) {
        const int part = phw[k * 3 + 0];
        const int row  = phw[k * 3 + 1];
        const int col  = phw[k * 3 + 2];
        const bool hit =
            (row >= ty0 - (FH_ / 2 - 1)) && (row <= ty0 + TILE_ - 1 + FH_ / 2) &&
            (col >= tx0 - (FW_ / 2 - 1)) && (col <= tx0 + TILE_ - 1 + FW_ / 2);
        if (hit) {
            const int idx = atomicAdd(&s_cnt, 1);
            // pack: part(8b) | row(9b) | col(9b)
            s_list[idx] = ((unsigned)part << 18) | ((unsigned)row << 9) | (unsigned)col;
        }
    }
    __syncthreads();
    const int cnt = s_cnt;

    // ---- Phase 2: accumulate owned pixels in registers ----
    // Thread t owns pixels (y_local = q*8 + (t>>5), x_local = t&31), q=0..3.
    const int xl = t & 31;
    const int yb = t >> 5;
    const int x  = tx0 + xl;

    float acc0 = 0.f, acc1 = 0.f, acc2 = 0.f, acc3 = 0.f;

    for (int k = 0; k < cnt; ++k) {
        const unsigned v = s_list[k];
        const int part = (int)(v >> 18);
        const int row  = (int)((v >> 9) & 511u);
        const int col  = (int)(v & 511u);

        const int j = x - col + (FW_ / 2);       // filter column, invariant over q
        if ((unsigned)j < (unsigned)FW_) {
            const float* f = filters + part * (FH_ * FW_) + j;
            const int i0 = ty0 + yb - row + (FH_ / 2);  // filter row for q=0
            int i;
            i = i0;      if ((unsigned)i < (unsigned)FH_) acc0 += f[i * FW_];
            i = i0 + 8;  if ((unsigned)i < (unsigned)FH_) acc1 += f[i * FW_];
            i = i0 + 16; if ((unsigned)i < (unsigned)FH_) acc2 += f[i * FW_];
            i = i0 + 24; if ((unsigned)i < (unsigned)FH_) acc3 += f[i * FW_];
        }
    }

    // ---- Epilogue: each pixel written exactly once (poisoned d_out is fully
    // overwritten; no zeroing pass required) ----
    const int yo = ty0 + yb;
    out[(yo +  0) * W_ + x] = acc0;
    out[(yo +  8) * W_ + x] = acc1;
    out[(yo + 16) * W_ + x] = acc2;
    out[(yo + 24) * W_ + x] = acc3;
}

extern "C" void kernel_launch(void* const* d_in, const int* in_sizes, int n_in,
                              void* d_out, int out_size, void* d_ws, size_t ws_size,
                              hipStream_t stream) {
    const int*   phw     = (const int*)d_in[0];
    const float* filters = (const float*)d_in[1];
    float*       out     = (float*)d_out;
    const int n = in_sizes[0] / 3;

    dim3 grid(W_ / TILE_, H_ / TILE_);
    render_tile_kernel<<<grid, 256, 0, stream>>>(phw, filters, out, n);
}

// Round 2
// 101.742 us; speedup vs baseline: 2.2388x; 2.2388x over previous
//
#include <hip/hip_runtime.h>

// RenderingModel: scatter-add of 64x64 filters at N particle positions onto a
// 512x512 canvas (cropped). Gather formulation: each block owns a 32x32 output
// tile AND a segment of the particle list (grid.z = segments). Phase 1 compacts
// the segment's particles whose 64x64 window intersects the tile into LDS;
// phase 2 accumulates predicated filter loads in registers; epilogue combines
// segments with global fp32 atomicAdd (d_out is zeroed via hipMemsetAsync).
//
// Why segments: with one block per tile the grid is 256 blocks = 1 wave/SIMD
// (9% occupancy measured) and the L2-latency of the hit loop is fully exposed.
// 8 segments -> 2048 blocks -> 8 blocks/CU (4KB LDS, 52 VGPR) = 32 waves/CU.

#define H_  512
#define W_  512
#define FH_ 64
#define FW_ 64
#define TILE_ 32
#define SEG_LEN_ 1024   // particles per segment; LDS list sized to this

__global__ __launch_bounds__(256)
void render_tile_kernel(const int* __restrict__ phw,
                        const float* __restrict__ filters,
                        float* __restrict__ out, int n) {
    __shared__ unsigned int s_list[SEG_LEN_];
    __shared__ int s_cnt;

    const int t   = threadIdx.x;
    const int tx0 = blockIdx.x * TILE_;
    const int ty0 = blockIdx.y * TILE_;
    const int k0  = blockIdx.z * SEG_LEN_;
    const int k1  = (k0 + SEG_LEN_ < n) ? (k0 + SEG_LEN_) : n;

    if (t == 0) s_cnt = 0;
    __syncthreads();

    // ---- Phase 1: bbox test + compaction of this segment into LDS ----
    // Particle (part,row,col) touches output y in [row-32, row+31],
    // x in [col-32, col+31]. Tile covers [ty0, ty0+31] x [tx0, tx0+31].
    for (int k = k0 + t; k < k1; k += 256) {
        const int part = phw[k * 3 + 0];
        const int row  = phw[k * 3 + 1];
        const int col  = phw[k * 3 + 2];
        const bool hit =
            (row >= ty0 - (FH_ / 2 - 1)) && (row <= ty0 + TILE_ - 1 + FH_ / 2) &&
            (col >= tx0 - (FW_ / 2 - 1)) && (col <= tx0 + TILE_ - 1 + FW_ / 2);
        if (hit) {
            const int idx = atomicAdd(&s_cnt, 1);
            // pack: part(8b) | row(9b) | col(9b)
            s_list[idx] = ((unsigned)part << 18) | ((unsigned)row << 9) | (unsigned)col;
        }
    }
    __syncthreads();
    const int cnt = s_cnt;

    // ---- Phase 2: accumulate owned pixels in registers ----
    // Thread t owns pixels (y_local = q*8 + (t>>5), x_local = t&31), q=0..3.
    const int xl = t & 31;
    const int yb = t >> 5;
    const int x  = tx0 + xl;

    float acc0 = 0.f, acc1 = 0.f, acc2 = 0.f, acc3 = 0.f;

#pragma unroll 2
    for (int k = 0; k < cnt; ++k) {
        const unsigned v = s_list[k];
        const int part = (int)(v >> 18);
        const int row  = (int)((v >> 9) & 511u);
        const int col  = (int)(v & 511u);

        const int j = x - col + (FW_ / 2);       // filter column, invariant over q
        if ((unsigned)j < (unsigned)FW_) {
            const float* f = filters + part * (FH_ * FW_) + j;
            const int i0 = ty0 + yb - row + (FH_ / 2);  // filter row for q=0
            int i;
            i = i0;      if ((unsigned)i < (unsigned)FH_) acc0 += f[i * FW_];
            i = i0 + 8;  if ((unsigned)i < (unsigned)FH_) acc1 += f[i * FW_];
            i = i0 + 16; if ((unsigned)i < (unsigned)FH_) acc2 += f[i * FW_];
            i = i0 + 24; if ((unsigned)i < (unsigned)FH_) acc3 += f[i * FW_];
        }
    }

    // ---- Epilogue: combine segments via device-scope fp32 atomics ----
    const int yo = ty0 + yb;
    atomicAdd(&out[(yo +  0) * W_ + x], acc0);
    atomicAdd(&out[(yo +  8) * W_ + x], acc1);
    atomicAdd(&out[(yo + 16) * W_ + x], acc2);
    atomicAdd(&out[(yo + 24) * W_ + x], acc3);
}

extern "C" void kernel_launch(void* const* d_in, const int* in_sizes, int n_in,
                              void* d_out, int out_size, void* d_ws, size_t ws_size,
                              hipStream_t stream) {
    const int*   phw     = (const int*)d_in[0];
    const float* filters = (const float*)d_in[1];
    float*       out     = (float*)d_out;
    const int n = in_sizes[0] / 3;

    // Output is accumulated with atomics -> must start from zero every call
    // (harness poisons d_out with 0xAA). Async memset is graph-capture safe.
    hipMemsetAsync(out, 0, (size_t)H_ * W_ * sizeof(float), stream);

    const int segs = (n + SEG_LEN_ - 1) / SEG_LEN_;
    dim3 grid(W_ / TILE_, H_ / TILE_, segs);
    render_tile_kernel<<<grid, 256, 0, stream>>>(phw, filters, out, n);
}